// Round 2
// baseline (254.933 us; speedup 1.0000x reference)
//
#include <hip/hip_runtime.h>

// x: (64, 4, 2, 256, 256) f32 ; tensors: (4,4,128,128,2,2,2,2,2) f32 ;
// bias: (4,128,128,2) f32 ; out: (64,4,2,128,128) f32
// sx=sy=256 even -> ix1=2x+1, iy1=2y+1 (clamp inert).
#define NUMN 64
#define CIN 4
#define COUT 4
#define SX 256
#define SY 256
#define NXX 128
#define NYY 128
#define YTILE 8
#define NSPLIT 2
#define NPER (NUMN / NSPLIT)

// R6: drop __syncthreads() from the loop. R5 post-mortem: the compiler emits
// a full `s_waitcnt vmcnt(0) lgkmcnt(0)` fence for __syncthreads even when
// the s_barrier is elided for a 1-wave workgroup. That drain sits right after
// the P1 global load is issued, so every iteration synchronously ate ~900cy
// of HBM latency — the 2-deep register prefetch was defeated (VALUBusy 27%,
// all pipes idle). In a 1-wave WG, same-wave DS ops execute in program order,
// so ds_write -> ds_read needs no barrier at all; the compiler's fine-grained
// lgkmcnt before first use is sufficient. #pragma unroll 4 register-renames
// the P0/P1 rotation so the prefetch depth is genuinely 2 iterations.
__global__ __launch_bounds__(64, 4)
void ttn_kernel(const float* __restrict__ x, const float* __restrict__ w,
                const float* __restrict__ bias, float* __restrict__ out)
{
    __shared__ float lds[2][256];   // 2 x 1 KB double buffer

    const int bid = blockIdx.x;
    const int xi = bid % NXX;
    const int yt = (bid / NXX) % (NYY / YTILE);
    const int ns = bid / (NXX * (NYY / YTILE));

    const int tid = threadIdx.x;                 // 0..63 (one wave)
    const int yl  = tid & (YTILE - 1);           // 0..7
    const int po  = tid >> 3;                    // p*2 + o
    const int p   = po >> 1;
    const int o   = po & 1;
    const int y   = yt * YTILE + yl;

    // ---- weight preamble: wr[c][q], q = 8i+4j+2k+l (float4 loads) ----
    float wr[CIN][16];
#pragma unroll
    for (int c = 0; c < CIN; ++c) {
        const float4* wp4 = (const float4*)(w +
            ((size_t)(((c * COUT + p) * NXX + xi) * NYY + y)) * 32);
#pragma unroll
        for (int j = 0; j < 8; ++j) {
            const float4 v = wp4[j];
            wr[c][2 * j]     = o ? v.y : v.x;
            wr[c][2 * j + 1] = o ? v.w : v.z;
        }
    }
    const float bv = bias[(((p * NXX + xi) * NYY + y) * 2) + o];

    // ---- staging map: thread -> (chunk mc = (c*2+d)*2 + r, 16B sub-offset) ----
    const int mc   = tid >> 2;                   // 0..15
    const int j0   = (tid & 3) * 4;              // float offset within 16-float chunk
    const int prow = mc >> 1;                    // c*2 + d
    const int r    = mc & 1;                     // which x-row of the pair
    const size_t nstr = (size_t)CIN * 2 * SX * SY;
    const size_t ostr = (size_t)COUT * 2 * NXX * NYY;

    const float* xg = x + (size_t)(ns * NPER) * nstr
                        + ((size_t)prow * SX + (2 * xi + r)) * SY + yt * 16 + j0;
    float* ob = out + (size_t)(ns * NPER) * ostr
                    + (size_t)po * (NXX * NYY) + xi * NYY + y;
    float* ldsw = &lds[0][0] + tid * 4;          // linear ds_write_b128 slot

    float4 P0 = *(const float4*)xg;              // prefetch n=0
    float4 P1 = *(const float4*)(xg + nstr);     // prefetch n=1

#pragma unroll 4
    for (int n = 0; n < NPER; ++n) {
        const int cur = n & 1;
        *(float4*)(ldsw + cur * 256) = P0;       // ds_write_b128 (waits only P0)
        P0 = P1;
        const int np = (n + 2 < NPER) ? (n + 2) : (NPER - 1);
        P1 = *(const float4*)(xg + (size_t)np * nstr);  // stays in flight

        // NO __syncthreads(): 1-wave WG, DS ops execute in program order on
        // the LDS pipe; wave_barrier is a zero-instruction scheduling fence
        // keeping the compiler from moving the reads above the write.
        __builtin_amdgcn_wave_barrier();

        const float2* l2 = (const float2*)&lds[cur][0];
        float acc = bv;
#pragma unroll
        for (int c = 0; c < CIN; ++c) {
            const float2 ae0 = l2[c * 32 +      yl];   // d0 row0 {a,e}
            const float2 bf0 = l2[c * 32 +  8 + yl];   // d0 row1 {b,f}
            const float2 ae1 = l2[c * 32 + 16 + yl];   // d1 row0 {a,e}
            const float2 bf1 = l2[c * 32 + 24 + yl];   // d1 row1 {b,f}
            const float a0 = ae0.x, e0 = ae0.y, b0 = bf0.x, f0 = bf0.y;
            const float a1 = ae1.x, e1 = ae1.y, b1 = bf1.x, f1 = bf1.y;
            const float ef00 = e0*f0, ef01 = e0*f1, ef10 = e1*f0, ef11 = e1*f1;
            const float ab00 = a0*b0, ab01 = a0*b1, ab10 = a1*b0, ab11 = a1*b1;
            const float* wq = wr[c];
            float t;
            t = ef00*wq[ 0] + ef01*wq[ 1] + ef10*wq[ 2] + ef11*wq[ 3];  acc += ab00 * t;
            t = ef00*wq[ 4] + ef01*wq[ 5] + ef10*wq[ 6] + ef11*wq[ 7];  acc += ab01 * t;
            t = ef00*wq[ 8] + ef01*wq[ 9] + ef10*wq[10] + ef11*wq[11];  acc += ab10 * t;
            t = ef00*wq[12] + ef01*wq[13] + ef10*wq[14] + ef11*wq[15];  acc += ab11 * t;
        }
        ob[(size_t)n * ostr] = acc;
        // dbuf safe without barrier: buf[cur] is rewritten only at n+2; same-wave
        // DS ops execute in order, so iter-n reads complete before that write.
    }
}

extern "C" void kernel_launch(void* const* d_in, const int* in_sizes, int n_in,
                              void* d_out, int out_size, void* d_ws, size_t ws_size,
                              hipStream_t stream) {
    const float* x    = (const float*)d_in[0];
    const float* w    = (const float*)d_in[1];
    const float* bias = (const float*)d_in[2];
    float* out = (float*)d_out;

    const int grid = NXX * (NYY / YTILE) * NSPLIT;  // 128*16*2 = 4096 blocks
    ttn_kernel<<<grid, 64, 0, stream>>>(x, w, bias, out);
}

// Round 4
// 238.476 us; speedup vs baseline: 1.0690x; 1.0690x over previous
//
#include <hip/hip_runtime.h>

// x: (64, 4, 2, 256, 256) f32 ; tensors: (4,4,128,128,2,2,2,2,2) f32 ;
// bias: (4,128,128,2) f32 ; out: (64,4,2,128,128) f32
// sx=sy=256 even -> ix1=2x+1, iy1=2y+1 (clamp inert).
#define NUMN 64
#define CIN 4
#define COUT 4
#define SX 256
#define SY 256
#define NXX 128
#define NYY 128
#define YTILE 32
#define NSPLIT 2
#define NPER (NUMN / NSPLIT)

// R8 == R7 resubmitted (R7's bench died in container acquisition — infra, not
// kernel). Rationale unchanged:
// Back to the R4 shape (4 waves / 256 threads: 128B-coalesced stores,
// 256B-contiguous x staging chunks — R5/R6's 1-wave shape amplified WRITE_SIZE
// 3x). Single change vs R4: replace __syncthreads() (which compiles to a full
// `s_waitcnt vmcnt(0) lgkmcnt(0)` drain — synchronously eating ~900cy of HBM
// latency for the prefetch load issued 5 instrs earlier, every iteration) with
// the verified 8-phase-template pattern: manual `s_waitcnt lgkmcnt(0)` (ds_write
// visibility is all the barrier needs) + raw s_barrier. Global prefetch loads
// now stay in flight ACROSS the barrier (counted vmcnt, never 0, per HK/AITER).
// Prefetch deepened to 3 so the ds_write's required load is ~3 iterations old.
__global__ __launch_bounds__(256, 2)
void ttn_kernel(const float* __restrict__ x, const float* __restrict__ w,
                const float* __restrict__ bias, float* __restrict__ out)
{
    __shared__ float lds[2][1024];   // 2 x 4 KB

    const int bid = blockIdx.x;
    const int xi = bid % NXX;
    const int yt = (bid / NXX) % (NYY / YTILE);
    const int ns = bid / (NXX * (NYY / YTILE));

    const int tid = threadIdx.x;
    const int yl  = tid & (YTILE - 1);
    const int po  = tid >> 5;                    // p*2 + o
    const int p   = po >> 1;
    const int o   = po & 1;
    const int y   = yt * YTILE + yl;

    // ---- weight preamble: wr[c][q], q = 8i+4j+2k+l (float4 loads) ----
    float wr[CIN][16];
#pragma unroll
    for (int c = 0; c < CIN; ++c) {
        const float4* wp4 = (const float4*)(w +
            ((size_t)(((c * COUT + p) * NXX + xi) * NYY + y)) * 32);
#pragma unroll
        for (int j = 0; j < 8; ++j) {
            const float4 v = wp4[j];
            wr[c][2 * j]     = o ? v.y : v.x;
            wr[c][2 * j + 1] = o ? v.w : v.z;
        }
    }
    const float bv = bias[(((p * NXX + xi) * NYY + y) * 2) + o];

    // ---- staging map: thread -> (chunk mc = (c*2+d)*2 + r, 16B sub-offset) ----
    const int mc   = tid >> 4;                   // 0..15
    const int j0   = (tid & 15) * 4;             // float offset within 64-float chunk
    const int prow = mc >> 1;                    // c*2 + d
    const int r    = mc & 1;                     // which x-row of the pair
    const size_t nstr = (size_t)CIN * 2 * SX * SY;
    const size_t ostr = (size_t)COUT * 2 * NXX * NYY;

    const float* xg = x + (size_t)(ns * NPER) * nstr
                        + ((size_t)prow * SX + (2 * xi + r)) * SY + yt * 64 + j0;
    float* ob = out + (size_t)(ns * NPER) * ostr
                    + (size_t)po * (NXX * NYY) + xi * NYY + y;
    float* ldsw = &lds[0][0] + tid * 4;          // linear ds_write_b128 slot

    float4 P0 = *(const float4*)xg;                        // prefetch n=0
    float4 P1 = *(const float4*)(xg + nstr);               // prefetch n=1
    float4 P2 = *(const float4*)(xg + 2 * nstr);           // prefetch n=2

    for (int n = 0; n < NPER; ++n) {
        const int cur = n & 1;
        *(float4*)(ldsw + cur * 1024) = P0;      // ds_write_b128 (counted vmcnt wait)
        P0 = P1;
        P1 = P2;
        const int np = (n + 3 < NPER) ? (n + 3) : (NPER - 1);
        P2 = *(const float4*)(xg + (size_t)np * nstr);  // stays in flight across barrier

        // __syncthreads() would emit `s_waitcnt vmcnt(0) lgkmcnt(0)` — draining
        // the prefetch we just issued. The barrier only needs the ds_write
        // visible: lgkmcnt(0) + raw s_barrier; vmcnt stays counted.
        asm volatile("s_waitcnt lgkmcnt(0)" ::: "memory");
        __builtin_amdgcn_s_barrier();
        asm volatile("" ::: "memory");   // pin ds_reads below the barrier
                                         // (s_barrier intrinsic is IntrNoMem)

        const float2* l2 = (const float2*)&lds[cur][0];
        float acc = bv;
#pragma unroll
        for (int c = 0; c < CIN; ++c) {
            const float2 ae0 = l2[c * 128 +       yl];   // d0 row0 {a,e}
            const float2 bf0 = l2[c * 128 +  32 + yl];   // d0 row1 {b,f}
            const float2 ae1 = l2[c * 128 +  64 + yl];   // d1 row0 {a,e}
            const float2 bf1 = l2[c * 128 +  96 + yl];   // d1 row1 {b,f}
            const float a0 = ae0.x, e0 = ae0.y, b0 = bf0.x, f0 = bf0.y;
            const float a1 = ae1.x, e1 = ae1.y, b1 = bf1.x, f1 = bf1.y;
            const float ef00 = e0*f0, ef01 = e0*f1, ef10 = e1*f0, ef11 = e1*f1;
            const float ab00 = a0*b0, ab01 = a0*b1, ab10 = a1*b0, ab11 = a1*b1;
            const float* wq = wr[c];
            float t;
            t = ef00*wq[ 0] + ef01*wq[ 1] + ef10*wq[ 2] + ef11*wq[ 3];  acc += ab00 * t;
            t = ef00*wq[ 4] + ef01*wq[ 5] + ef10*wq[ 6] + ef11*wq[ 7];  acc += ab01 * t;
            t = ef00*wq[ 8] + ef01*wq[ 9] + ef10*wq[10] + ef11*wq[11];  acc += ab10 * t;
            t = ef00*wq[12] + ef01*wq[13] + ef10*wq[14] + ef11*wq[15];  acc += ab11 * t;
        }
        ob[(size_t)n * ostr] = acc;
        // single barrier/iter safe: buf[cur] rewritten only at n+2; every wave's
        // iter-n ds_reads are drained by its own lgkmcnt(0) before it arrives at
        // barrier n+1, which wave-A must pass before its n+2 ds_write.
    }
}

extern "C" void kernel_launch(void* const* d_in, const int* in_sizes, int n_in,
                              void* d_out, int out_size, void* d_ws, size_t ws_size,
                              hipStream_t stream) {
    const float* x    = (const float*)d_in[0];
    const float* w    = (const float*)d_in[1];
    const float* bias = (const float*)d_in[2];
    float* out = (float*)d_out;

    const int grid = NXX * (NYY / YTILE) * NSPLIT;  // 128*4*2 = 1024 blocks
    ttn_kernel<<<grid, 256, 0, stream>>>(x, w, bias, out);
}